// Round 14
// baseline (131.459 us; speedup 1.0000x reference)
//
#include <hip/hip_runtime.h>
#include <hip/hip_bf16.h>
#include <math.h>

#define SEQ 8192
#define DIN 512
#define DH  64
#define BK  64                // K/V rows per iteration
#define LDP 72                // padded LDS row stride (bf16); 144B = 16B-aligned
#define SXP 516               // padded fp32 x row stride (pgemm)

typedef float f32x4 __attribute__((ext_vector_type(4)));
typedef short short8 __attribute__((ext_vector_type(8)));
typedef ushort us4 __attribute__((ext_vector_type(4)));

static __device__ __forceinline__ ushort bf16_of(float v) {
  __hip_bfloat16 h = __float2bfloat16(v);
  return *reinterpret_cast<ushort*>(&h);
}
static __device__ __forceinline__ float f_of_bf16(ushort u) {
  __hip_bfloat16 h;
  *reinterpret_cast<ushort*>(&h) = u;
  return __bfloat162float(h);
}
static __device__ __forceinline__ f32x4 mfma16(short8 a, short8 b, f32x4 c) {
  return __builtin_amdgcn_mfma_f32_16x16x32_bf16(a, b, c, 0, 0, 0);
}
static __device__ __forceinline__ uint pack_bf16(float a, float b) {
  __hip_bfloat162 h2 = __float22bfloat162_rn(make_float2(a, b));
  return *reinterpret_cast<uint*>(&h2);
}
// K-row permutation (R12-proven): physical row p -> LDS slot, so the S^T
// C-layout ownership coincides with PV B-operand k-ownership, making the
// P^T fragment pure register renaming.
static __device__ __forceinline__ int slot_of(int p) {
  return ((((p >> 2) & 1) * 2 + (p >> 5)) << 4) | (((p >> 3) & 3) << 2) | (p & 3);
}

// ---------------------------------------------------------------------------
// Kernel 1 (pgemm v4, R13-proven, unchanged): prep folded in; W read fp32,
// scale/transpose/hi-lo split in-register; ping-pong prefetch of W values.
// ---------------------------------------------------------------------------
__global__ __launch_bounds__(256, 2) void pgemm_kernel(
    const float* __restrict__ x,  const float* __restrict__ Wq,
    const float* __restrict__ Wk, const float* __restrict__ Wv,
    ushort* __restrict__ Qh, ushort* __restrict__ Ql,
    ushort* __restrict__ Kh, ushort* __restrict__ Kl,
    ushort* __restrict__ Vt) {
  __shared__ float sx[16][SXP];               // 33 KB; reused as merge buf
  float* mb = &sx[0][0];

  const int tid = threadIdx.x;
  const int wv = tid >> 6, lane = tid & 63;
  const int ln = lane & 15, qd = lane >> 4;
  const int rb = blockIdx.x * 16;

  {
    const float4* xg = reinterpret_cast<const float4*>(x + (size_t)rb * DIN);
#pragma unroll
    for (int j = 0; j < 8; ++j) {
      const int idx = tid + 256 * j;
      const int row = idx >> 7;
      const int col = (idx & 127) * 4;
      *reinterpret_cast<float4*>(&sx[row][col]) = xg[idx];
    }
  }
  __syncthreads();

  f32x4 acc[3][4];
#pragma unroll
  for (int m = 0; m < 3; ++m)
#pragma unroll
    for (int nt = 0; nt < 4; ++nt)
#pragma unroll
      for (int i = 0; i < 4; ++i) acc[m][nt][i] = 0.f;

  const int kb = wv * 128;
  const int wbase = (kb + qd * 8) * 64 + ln;

  float wf[2][32];
#define LDW(kt_, m_, buf_)                                                     \
  do {                                                                         \
    const float* W_ = ((m_) == 0) ? Wq : (((m_) == 1) ? Wk : Wv);              \
    const int o_ = wbase + (kt_) * 32 * 64;                                    \
    _Pragma("unroll") for (int nt = 0; nt < 4; ++nt)                           \
      _Pragma("unroll") for (int j = 0; j < 8; ++j)                            \
        wf[buf_][nt * 8 + j] = W_[o_ + j * 64 + nt * 16];                      \
  } while (0)

  LDW(0, 0, 0);
#pragma unroll
  for (int kt = 0; kt < 4; ++kt) {
    const int k0 = kb + kt * 32;
    float xs[8];
    *reinterpret_cast<float4*>(xs) =
        *reinterpret_cast<const float4*>(&sx[ln][k0 + qd * 8]);
    *reinterpret_cast<float4*>(xs + 4) =
        *reinterpret_cast<const float4*>(&sx[ln][k0 + qd * 8 + 4]);
    ushort ah[8] __attribute__((aligned(16)));
    ushort al[8] __attribute__((aligned(16)));
#pragma unroll
    for (int j = 0; j < 8; ++j) {
      const ushort h = bf16_of(xs[j]);
      ah[j] = h;
      al[j] = bf16_of(xs[j] - f_of_bf16(h));
    }
    const short8 Ah = *reinterpret_cast<short8*>(ah);
    const short8 Al = *reinterpret_cast<short8*>(al);
#pragma unroll
    for (int m = 0; m < 3; ++m) {
      const int g = kt * 3 + m;
      const int buf = g & 1;
      if (g < 11) {
        const int gn = g + 1;
        LDW(gn / 3, gn % 3, buf ^ 1);
      }
      const float scale = (m == 0) ? 0.125f * 1.44269504088896f : 1.0f;
#pragma unroll
      for (int nt = 0; nt < 4; ++nt) {
        ushort bh8[8] __attribute__((aligned(16)));
        ushort bl8[8] __attribute__((aligned(16)));
#pragma unroll
        for (int j = 0; j < 8; ++j) {
          const float v = wf[buf][nt * 8 + j] * scale;
          const ushort h = bf16_of(v);
          bh8[j] = h;
          bl8[j] = bf16_of(v - f_of_bf16(h));
        }
        const short8 bh = *reinterpret_cast<short8*>(bh8);
        const short8 bl = *reinterpret_cast<short8*>(bl8);
        acc[m][nt] = mfma16(Ah, bh, acc[m][nt]);
        acc[m][nt] = mfma16(Ah, bl, acc[m][nt]);
        acc[m][nt] = mfma16(Al, bh, acc[m][nt]);
      }
    }
  }
#undef LDW

  const int eidx = (qd * 4) * 64 + ln;
  __syncthreads();
  if (wv >= 2) {
    float* b = mb + (size_t)(wv - 2) * 3072;
#pragma unroll
    for (int m = 0; m < 3; ++m)
#pragma unroll
      for (int nt = 0; nt < 4; ++nt)
#pragma unroll
        for (int r = 0; r < 4; ++r)
          b[m * 1024 + eidx + r * 64 + nt * 16] = acc[m][nt][r];
  }
  __syncthreads();
  if (wv < 2) {
    const float* b = mb + (size_t)wv * 3072;
#pragma unroll
    for (int m = 0; m < 3; ++m)
#pragma unroll
      for (int nt = 0; nt < 4; ++nt)
#pragma unroll
        for (int r = 0; r < 4; ++r)
          acc[m][nt][r] += b[m * 1024 + eidx + r * 64 + nt * 16];
  }
  __syncthreads();
  if (wv == 1) {
#pragma unroll
    for (int m = 0; m < 3; ++m)
#pragma unroll
      for (int nt = 0; nt < 4; ++nt)
#pragma unroll
        for (int r = 0; r < 4; ++r)
          mb[m * 1024 + eidx + r * 64 + nt * 16] = acc[m][nt][r];
  }
  __syncthreads();
  if (wv == 0) {
#pragma unroll
    for (int m = 0; m < 3; ++m)
#pragma unroll
      for (int nt = 0; nt < 4; ++nt)
#pragma unroll
        for (int r = 0; r < 4; ++r)
          acc[m][nt][r] += mb[m * 1024 + eidx + r * 64 + nt * 16];

#pragma unroll
    for (int m = 0; m < 2; ++m) {
      ushort* H = (m == 0) ? Qh : Kh;
      ushort* L = (m == 0) ? Ql : Kl;
#pragma unroll
      for (int nt = 0; nt < 4; ++nt)
#pragma unroll
        for (int r = 0; r < 4; ++r) {
          const float v = acc[m][nt][r];
          const int row = rb + qd * 4 + r;
          const int col = nt * 16 + ln;
          const ushort h = bf16_of(v);
          H[(size_t)row * DH + col] = h;
          L[(size_t)row * DH + col] = bf16_of(v - f_of_bf16(h));
        }
    }
#pragma unroll
    for (int nt = 0; nt < 4; ++nt) {
      ushort vp[4] __attribute__((aligned(8)));
#pragma unroll
      for (int r = 0; r < 4; ++r) vp[r] = bf16_of(acc[2][nt][r]);
      *reinterpret_cast<us4*>(Vt + (size_t)(nt * 16 + ln) * SEQ + rb + qd * 4) =
          *reinterpret_cast<us4*>(vp);
    }
  }
}

// ---------------------------------------------------------------------------
// Kernel 2 (flash v6): R12 structure (2 Q-sets/wave, permuted-K gather-free
// P^T) with V SINGLE-BUFFERED (K stays double-buffered) -> LDS 55.3->45 KB,
// 3 blocks/CU under launch_bounds(256,3).  Templated on SG so the grid can
// grow to 1024 (SG=16) when ws_size permits — 3 resident blocks need >512
// blocks to matter.  2 barriers/iter (pre-V-store + post-store).
// ---------------------------------------------------------------------------
template <int SGv>
__global__ __launch_bounds__(256, 3) void flash_kernel(
    const ushort* __restrict__ Qh, const ushort* __restrict__ Ql,
    const ushort* __restrict__ Kh, const ushort* __restrict__ Kl,
    const ushort* __restrict__ Vt,
    ushort* __restrict__ Opart, float* __restrict__ Mpart,
    float* __restrict__ Lpart) {
  const int CHUNKv = SEQ / SGv;
  const int NITv   = CHUNKv / BK;
  __shared__ __attribute__((aligned(16))) ushort sKh[2][BK][LDP];  // 18.4 KB
  __shared__ __attribute__((aligned(16))) ushort sKl[2][BK][LDP];  // 18.4 KB
  __shared__ __attribute__((aligned(16))) ushort sVt[DH][LDP];     //  9.2 KB

  const int tid  = threadIdx.x;
  const int wv   = tid >> 6;
  const int lane = tid & 63;
  const int ln   = lane & 15;
  const int qd   = lane >> 4;
  const int bid  = blockIdx.x;
  const int sg   = bid % SGv;
  const int qt   = bid / SGv;       // 128-row Q tiles
  const int qrow0  = qt * 128 + wv * 32;   // set s adds s*16
  const int k0base = sg * CHUNKv;

  const int r0 = tid >> 3, g0 = (tid & 7) * 8;
  const int r1 = r0 + 32,  g1 = g0;
  const int sr0 = slot_of(r0), sr1 = slot_of(r1);   // permuted K slots

  const ushort one_u = (ln == 0) ? (ushort)0x3F80 : (ushort)0;
  short8 afr1;
#pragma unroll
  for (int j = 0; j < 8; ++j) afr1[j] = (short)one_u;

  short8 bqh[2][2], bql[2][2];
#pragma unroll
  for (int s = 0; s < 2; ++s)
#pragma unroll
    for (int kt = 0; kt < 2; ++kt) {
      bqh[s][kt] = *reinterpret_cast<const short8*>(
          Qh + (size_t)(qrow0 + s * 16 + ln) * DH + kt * 32 + qd * 8);
      bql[s][kt] = *reinterpret_cast<const short8*>(
          Ql + (size_t)(qrow0 + s * 16 + ln) * DH + kt * 32 + qd * 8);
    }

  f32x4 accO[2][4], accL[2];
  float m_run[2] = {-INFINITY, -INFINITY};
#pragma unroll
  for (int s = 0; s < 2; ++s) {
#pragma unroll
    for (int nt = 0; nt < 4; ++nt)
#pragma unroll
      for (int i = 0; i < 4; ++i) accO[s][nt][i] = 0.f;
#pragma unroll
    for (int i = 0; i < 4; ++i) accL[s][i] = 0.f;
  }

  uint4 pk0, pk1, pl0, pl1, pv0, pv1;
#define LOAD_TILES(k0_)                                                        \
  do {                                                                         \
    pk0 = *reinterpret_cast<const uint4*>(Kh + (size_t)((k0_) + r0) * DH + g0);\
    pk1 = *reinterpret_cast<const uint4*>(Kh + (size_t)((k0_) + r1) * DH + g1);\
    pl0 = *reinterpret_cast<const uint4*>(Kl + (size_t)((k0_) + r0) * DH + g0);\
    pl1 = *reinterpret_cast<const uint4*>(Kl + (size_t)((k0_) + r1) * DH + g1);\
    pv0 = *reinterpret_cast<const uint4*>(Vt + (size_t)r0 * SEQ + (k0_) + g0); \
    pv1 = *reinterpret_cast<const uint4*>(Vt + (size_t)r1 * SEQ + (k0_) + g1); \
  } while (0)
#define STORE_K(b_)                                                            \
  do {                                                                         \
    *reinterpret_cast<uint4*>(&sKh[b_][sr0][g0]) = pk0;                        \
    *reinterpret_cast<uint4*>(&sKh[b_][sr1][g1]) = pk1;                        \
    *reinterpret_cast<uint4*>(&sKl[b_][sr0][g0]) = pl0;                        \
    *reinterpret_cast<uint4*>(&sKl[b_][sr1][g1]) = pl1;                        \
  } while (0)
#define STORE_V()                                                              \
  do {                                                                         \
    *reinterpret_cast<uint4*>(&sVt[r0][g0]) = pv0;                             \
    *reinterpret_cast<uint4*>(&sVt[r1][g1]) = pv1;                             \
  } while (0)

  LOAD_TILES(k0base);
  STORE_K(0);
  STORE_V();
  __syncthreads();

  for (int it = 0; it < NITv; ++it) {
    const int cur = it & 1;
    const int k0n = k0base + ((it + 1 < NITv) ? (it + 1) : it) * BK;
    LOAD_TILES(k0n);          // next iter's globals, hidden under compute

    // S^T tiles (64x16 per set): each K-fragment read feeds both sets
    f32x4 accS[2][4];
#pragma unroll
    for (int nt = 0; nt < 4; ++nt) {
#pragma unroll
      for (int s = 0; s < 2; ++s)
#pragma unroll
        for (int i = 0; i < 4; ++i) accS[s][nt][i] = 0.f;
      const short8 kh0 = *reinterpret_cast<const short8*>(&sKh[cur][nt * 16 + ln][qd * 8]);
      const short8 kh1 = *reinterpret_cast<const short8*>(&sKh[cur][nt * 16 + ln][32 + qd * 8]);
      const short8 kl0 = *reinterpret_cast<const short8*>(&sKl[cur][nt * 16 + ln][qd * 8]);
      const short8 kl1 = *reinterpret_cast<const short8*>(&sKl[cur][nt * 16 + ln][32 + qd * 8]);
#pragma unroll
      for (int s = 0; s < 2; ++s) {
        accS[s][nt] = mfma16(kh0, bqh[s][0], accS[s][nt]);
        accS[s][nt] = mfma16(kh1, bqh[s][1], accS[s][nt]);
        accS[s][nt] = mfma16(kh0, bql[s][0], accS[s][nt]);
        accS[s][nt] = mfma16(kh1, bql[s][1], accS[s][nt]);
        accS[s][nt] = mfma16(kl0, bqh[s][0], accS[s][nt]);
        accS[s][nt] = mfma16(kl1, bqh[s][1], accS[s][nt]);
      }
    }

    // per-lane online softmax (lane owns q-row = ln of its set), exp2 domain
    uint pkd[2][4][2];
#pragma unroll
    for (int s = 0; s < 2; ++s) {
      float tmax = fmaxf(
          fmaxf(fmaxf(accS[s][0][0], accS[s][0][1]), fmaxf(accS[s][0][2], accS[s][0][3])),
          fmaxf(fmaxf(accS[s][1][0], accS[s][1][1]), fmaxf(accS[s][1][2], accS[s][1][3])));
      tmax = fmaxf(tmax, fmaxf(
          fmaxf(fmaxf(accS[s][2][0], accS[s][2][1]), fmaxf(accS[s][2][2], accS[s][2][3])),
          fmaxf(fmaxf(accS[s][3][0], accS[s][3][1]), fmaxf(accS[s][3][2], accS[s][3][3]))));
      tmax = fmaxf(tmax, __shfl_xor(tmax, 16));
      tmax = fmaxf(tmax, __shfl_xor(tmax, 32));
      const float mnew  = fmaxf(m_run[s], tmax);
      const float alpha = exp2f(m_run[s] - mnew);
      m_run[s] = mnew;
#pragma unroll
      for (int nt = 0; nt < 4; ++nt) {
        const float p0 = exp2f(accS[s][nt][0] - mnew);
        const float p1 = exp2f(accS[s][nt][1] - mnew);
        const float p2 = exp2f(accS[s][nt][2] - mnew);
        const float p3 = exp2f(accS[s][nt][3] - mnew);
        pkd[s][nt][0] = pack_bf16(p0, p1);
        pkd[s][nt][1] = pack_bf16(p2, p3);
#pragma unroll
        for (int i = 0; i < 4; ++i) accO[s][nt][i] *= alpha;
      }
      accL[s][0] *= alpha;
    }

    // O^T += V^T · P^T ; l += 1~ · P^T — P^T frag is register renaming
#pragma unroll
    for (int kt2 = 0; kt2 < 2; ++kt2) {
      short8 pfrag[2];
#pragma unroll
      for (int s = 0; s < 2; ++s) {
        uint4 du;
        du.x = pkd[s][kt2][0];
        du.y = pkd[s][kt2][1];
        du.z = pkd[s][kt2 + 2][0];
        du.w = pkd[s][kt2 + 2][1];
        pfrag[s] = *reinterpret_cast<short8*>(&du);
      }
#pragma unroll
      for (int nt2 = 0; nt2 < 4; ++nt2) {
        const short8 vA = *reinterpret_cast<const short8*>(
            &sVt[nt2 * 16 + ln][kt2 * 32 + qd * 8]);
        accO[0][nt2] = mfma16(vA, pfrag[0], accO[0][nt2]);
        accO[1][nt2] = mfma16(vA, pfrag[1], accO[1][nt2]);
      }
      accL[0] = mfma16(afr1, pfrag[0], accL[0]);
      accL[1] = mfma16(afr1, pfrag[1], accL[1]);
    }

    if (it + 1 < NITv) {
      __syncthreads();        // all waves done reading sVt (and sK[cur])
      STORE_K(cur ^ 1);
      STORE_V();
      __syncthreads();        // new V/K visible before next iter's reads
    }
  }
#undef LOAD_TILES
#undef STORE_K
#undef STORE_V

  // epilogue per set: lane holds q-row = qrow0 + s*16 + ln
#pragma unroll
  for (int s = 0; s < 2; ++s) {
    const int qrow = qrow0 + s * 16 + ln;
    ushort* Ob = Opart + ((size_t)sg * SEQ + qrow) * DH;
#pragma unroll
    for (int nt = 0; nt < 4; ++nt) {
      ushort op[4] __attribute__((aligned(8)));
#pragma unroll
      for (int r = 0; r < 4; ++r) op[r] = bf16_of(accO[s][nt][r]);
      *reinterpret_cast<us4*>(Ob + nt * 16 + qd * 4) =
          *reinterpret_cast<us4*>(op);
    }
    if (qd == 0) {
      Mpart[(size_t)sg * SEQ + qrow] = m_run[s];
      Lpart[(size_t)sg * SEQ + qrow] = accL[s][0];
    }
  }
}

// ---------------------------------------------------------------------------
// Kernel 3: merge of the SG seq-split partials (exp2 domain), vectorized x4.
// ---------------------------------------------------------------------------
template <int SGv>
__global__ __launch_bounds__(256) void merge_kernel(
    const ushort* __restrict__ Opart, const float* __restrict__ Mpart,
    const float* __restrict__ Lpart, float* __restrict__ out) {
  const int idx = blockIdx.x * 256 + threadIdx.x;   // 0 .. SEQ*16
  const int row = idx >> 4;
  const int c4  = (idx & 15) * 4;

  float m[SGv];
  float M = -INFINITY;
#pragma unroll
  for (int i = 0; i < SGv; ++i) {
    m[i] = Mpart[(size_t)i * SEQ + row];
    M = fmaxf(M, m[i]);
  }
  float L = 0.f;
  float a0 = 0.f, a1 = 0.f, a2 = 0.f, a3 = 0.f;
#pragma unroll
  for (int i = 0; i < SGv; ++i) {
    const float w = exp2f(m[i] - M);
    L += w * Lpart[(size_t)i * SEQ + row];
    const us4 o = *reinterpret_cast<const us4*>(
        Opart + ((size_t)i * SEQ + row) * DH + c4);
    a0 += w * f_of_bf16(o[0]);
    a1 += w * f_of_bf16(o[1]);
    a2 += w * f_of_bf16(o[2]);
    a3 += w * f_of_bf16(o[3]);
  }
  const float rL = 1.0f / L;
  float4 res = make_float4(a0 * rL, a1 * rL, a2 * rL, a3 * rL);
  *reinterpret_cast<float4*>(out + (size_t)row * DH + c4) = res;
}

// ---------------------------------------------------------------------------
extern "C" void kernel_launch(void* const* d_in, const int* in_sizes, int n_in,
                              void* d_out, int out_size, void* d_ws, size_t ws_size,
                              hipStream_t stream) {
  const float* x  = (const float*)d_in[0];
  const float* Wq = (const float*)d_in[1];
  const float* Wk = (const float*)d_in[2];
  const float* Wv = (const float*)d_in[3];
  float* out = (float*)d_out;

  const size_t S64 = (size_t)SEQ * DH;        // 524288 elems
  ushort* Qh = (ushort*)d_ws;
  ushort* Ql = Qh + S64;
  ushort* Kh = Ql + S64;
  ushort* Kl = Kh + S64;
  ushort* Vt = Kl + S64;
  ushort* Op = Vt + S64;                      // [SG][SEQ][DH] bf16

  // SG=16 needs: 5*S64*2 + 16*S64*2 + 2*16*SEQ*4 = 23,068,672 B.
  // SG=8 (fallback, R13-proven footprint): 14,155,776 B.
  const size_t NEED16 = 5 * S64 * 2 + 16 * S64 * 2 + (size_t)2 * 16 * SEQ * 4;

  pgemm_kernel<<<SEQ / 16, 256, 0, stream>>>(x, Wq, Wk, Wv, Qh, Ql, Kh, Kl, Vt);

  if (ws_size >= NEED16) {
    float* Mp = (float*)(Op + (size_t)16 * S64);
    float* Lp = Mp + (size_t)16 * SEQ;
    flash_kernel<16><<<(SEQ / 128) * 16, 256, 0, stream>>>(
        Qh, Ql, Kh, Kl, Vt, Op, Mp, Lp);
    merge_kernel<16><<<(SEQ * 16) / 256, 256, 0, stream>>>(Op, Mp, Lp, out);
  } else {
    float* Mp = (float*)(Op + (size_t)8 * S64);
    float* Lp = Mp + (size_t)8 * SEQ;
    flash_kernel<8><<<(SEQ / 128) * 8, 256, 0, stream>>>(
        Qh, Ql, Kh, Kl, Vt, Op, Mp, Lp);
    merge_kernel<8><<<(SEQ * 16) / 256, 256, 0, stream>>>(Op, Mp, Lp, out);
  }
}